// Round 1
// baseline (216.181 us; speedup 1.0000x reference)
//
#include <hip/hip_runtime.h>
#include <math.h>

#define NQ 22
#define NH 9        // high qubits 0..8   (h = x >> 13)
#define NL 13       // low qubits 9..21   (l = x & 8191)
#define HD 512      // 2^NH
#define LD 8192     // 2^NL
#define CHUNK 8192

// ---------------- K0: tables ----------------
// w[h]   = prod over high qubits of (bit ? sin a : cos a), a = (feat+params0)/2
// u[l]   = same over low qubits
// sigh[h]= parity of high-high edges
// lowvs[l] = V (bits 0..8, bit (8-i) = parity(l & cross-mask_i)) | (sigl << 9)
// cs1/cs2 = (cos, sin) of params[1]/2, params[2]/2
// rowSum zeroed here (K4 accumulates atomically).
__global__ void k0_tables(const float* feat, const float* adj, const float* params,
                          float* w, float* u, unsigned* sigh, unsigned* lowvs,
                          float2* cs1, float2* cs2, float* rowSum) {
    int t = blockIdx.x * blockDim.x + threadIdx.x;
    if (t < NQ) {
        cs1[t] = make_float2(cosf(0.5f * params[NQ + t]),     sinf(0.5f * params[NQ + t]));
        cs2[t] = make_float2(cosf(0.5f * params[2*NQ + t]),   sinf(0.5f * params[2*NQ + t]));
    }
    if (t < HD) {
        int h = t;
        unsigned par = 0;
        float prod = 1.f;
        for (int i = 0; i < NH; i++) {
            int bi = (h >> (NH - 1 - i)) & 1;
            float a = 0.5f * (feat[i] + params[i]);
            prod *= bi ? sinf(a) : cosf(a);
            if (bi) {
                for (int j2 = i + 1; j2 < NH; j2++)
                    if (((h >> (NH - 1 - j2)) & 1) && adj[i * NQ + j2] > 0.f) par ^= 1u;
            }
        }
        w[h] = prod;
        sigh[h] = par;
        rowSum[h] = 0.f;
    }
    if (t < LD) {
        int l = t;
        unsigned par = 0;
        float prod = 1.f;
        for (int qi = 0; qi < NL; qi++) {
            int q = NH + qi;                     // 9..21
            int b = (l >> (NQ - 1 - q)) & 1;
            float a = 0.5f * (feat[q] + params[q]);
            prod *= b ? sinf(a) : cosf(a);
            if (b) {
                for (int qj = qi + 1; qj < NL; qj++) {
                    int q2 = NH + qj;
                    if (((l >> (NQ - 1 - q2)) & 1) && adj[q * NQ + q2] > 0.f) par ^= 1u;
                }
            }
        }
        unsigned V = 0;
        for (int i = 0; i < NH; i++) {
            unsigned p2 = 0;
            for (int qj = 0; qj < NL; qj++) {
                int q2 = NH + qj;
                if (((l >> (NQ - 1 - q2)) & 1) && adj[i * NQ + q2] > 0.f) p2 ^= 1u;
            }
            V |= p2 << (NH - 1 - i);
        }
        u[l] = prod;
        lowvs[l] = V | (par << NH);
    }
}

// ---------------- K1/K3: low-qubit pass (contiguous 8192-chunk in LDS) ----------------
// stride 2^k within chunk <-> qubit q = 21-k, k = 0..12.
__global__ __launch_bounds__(256) void k_low(float* state, const float* w, const float* u,
                                             const unsigned* sigh, const unsigned* lowvs,
                                             const float2* cs, int init) {
    __shared__ float chunk[CHUNK];
    const int h = blockIdx.x;
    const int t = threadIdx.x;

    if (init) {
        float wh = w[h];
        unsigned sh = sigh[h];
        for (int it = 0; it < 32; it++) {
            int m = t + 256 * it;
            unsigned lv = lowvs[m];
            unsigned sgn = sh ^ (lv >> NH) ^ (unsigned)__popc(h & (lv & 0x1FFu));
            float v = wh * u[m];
            chunk[m] = (sgn & 1u) ? -v : v;
        }
    } else {
        const float* src = state + (size_t)h * CHUNK;
        for (int it = 0; it < 32; it++) { int m = t + 256 * it; chunk[m] = src[m]; }
    }

    for (int k = 0; k < NL; k++) {
        int q = NQ - 1 - k;                      // 21..9
        float c = cs[q].x, s = cs[q].y;
        unsigned msk = (1u << k) - 1u;
        __syncthreads();
        for (int i = 0; i < 16; i++) {
            unsigned p = t + 256u * i;           // 4096 pairs
            unsigned i0 = ((p >> k) << (k + 1)) | (p & msk);
            unsigned i1 = i0 | (1u << k);
            float a = chunk[i0], b = chunk[i1];
            chunk[i0] = c * a - s * b;
            chunk[i1] = s * a + c * b;
        }
    }
    __syncthreads();
    float* dst = state + (size_t)h * CHUNK;
    for (int it = 0; it < 32; it++) { int m = t + 256 * it; dst[m] = chunk[m]; }
}

// ---------------- K2: high-qubit pass (tile [512 m][16 r]) + optional sign ----------------
// m-stride 2^k <-> qubit q = 8-k, k = 0..8.
__global__ __launch_bounds__(256) void k_high(float* state, const unsigned* sigh,
                                              const unsigned* lowvs, const float2* cs) {
    __shared__ float tile[CHUNK];                // [m][16]
    const int rb = blockIdx.x * 16;
    const int t = threadIdx.x;
    const int j = t & 15, g = t >> 4;

    for (int it = 0; it < 32; it++) {
        int m = g + 16 * it;
        tile[m * 16 + j] = state[(size_t)m * LD + rb + j];
    }
    for (int k = 0; k < NH; k++) {
        int q = NH - 1 - k;                      // 8..0
        float c = cs[q].x, s = cs[q].y;
        unsigned msk = (1u << k) - 1u;
        __syncthreads();
        for (int i = 0; i < 16; i++) {
            unsigned p = g + 16u * i;            // 256 m-pairs
            unsigned m0 = ((p >> k) << (k + 1)) | (p & msk);
            unsigned m1 = m0 | (1u << k);
            float a = tile[m0 * 16 + j], b = tile[m1 * 16 + j];
            tile[m0 * 16 + j] = c * a - s * b;
            tile[m1 * 16 + j] = s * a + c * b;
        }
    }
    __syncthreads();
    int r = rb + j;
    unsigned lv = lowvs[r];
    unsigned sl = (lv >> NH) & 1u;
    unsigned V  = lv & 0x1FFu;
    for (int it = 0; it < 32; it++) {
        int m = g + 16 * it;
        float v = tile[m * 16 + j];
        unsigned sgn = sigh[m] ^ sl ^ (unsigned)__popc((unsigned)m & V);
        if (sgn & 1u) v = -v;
        state[(size_t)m * LD + rb + j] = v;
    }
}

// ---------------- K4: final high pass + probs + marginals (no state write) ----------------
__global__ __launch_bounds__(256) void k_high_final(const float* state, const float2* cs,
                                                    float* rowSum, float* colSum) {
    __shared__ float tile[CHUNK];
    __shared__ float rowAcc[HD];
    __shared__ float colAcc[16];
    const int rb = blockIdx.x * 16;
    const int t = threadIdx.x;
    const int j = t & 15, g = t >> 4;

    rowAcc[t] = 0.f; rowAcc[t + 256] = 0.f;
    if (t < 16) colAcc[t] = 0.f;

    for (int it = 0; it < 32; it++) {
        int m = g + 16 * it;
        tile[m * 16 + j] = state[(size_t)m * LD + rb + j];
    }
    for (int k = 0; k < NH; k++) {
        int q = NH - 1 - k;
        float c = cs[q].x, s = cs[q].y;
        unsigned msk = (1u << k) - 1u;
        __syncthreads();
        for (int i = 0; i < 16; i++) {
            unsigned p = g + 16u * i;
            unsigned m0 = ((p >> k) << (k + 1)) | (p & msk);
            unsigned m1 = m0 | (1u << k);
            float a = tile[m0 * 16 + j], b = tile[m1 * 16 + j];
            tile[m0 * 16 + j] = c * a - s * b;
            tile[m1 * 16 + j] = s * a + c * b;
        }
    }
    __syncthreads();
    float cpart = 0.f;
    for (int it = 0; it < 32; it++) {
        int m = g + 16 * it;
        float v = tile[m * 16 + j];
        float p2 = v * v;
        cpart += p2;
        atomicAdd(&rowAcc[m], p2);
    }
    atomicAdd(&colAcc[j], cpart);
    __syncthreads();
    // rowSum: global atomic accumulation (zeroed in K0)
    atomicAdd(&rowSum[t],       rowAcc[t]);
    atomicAdd(&rowSum[t + 256], rowAcc[t + 256]);
    if (t < 16) colSum[rb + t] = colAcc[t];
}

// ---------------- K5: expectations ----------------
__global__ __launch_bounds__(512) void k_expect(const float* rowSum, const float* colSum,
                                                float* out) {
    __shared__ float red[512];
    const int t = threadIdx.x;
    float rs = rowSum[t];
    // high qubits 0..8: bit at position (8-q) of row index
    for (int q = 0; q < NH; q++) {
        float v = ((t >> (NH - 1 - q)) & 1) ? -rs : rs;
        red[t] = v;
        __syncthreads();
        for (int off = 256; off > 0; off >>= 1) {
            if (t < off) red[t] += red[t + off];
            __syncthreads();
        }
        if (t == 0) out[q] = red[0];
        __syncthreads();
    }
    // low qubits 9..21: bit at position (12-qi) of col index
    float part[NL];
    for (int i = 0; i < NL; i++) part[i] = 0.f;
    for (int it = 0; it < 16; it++) {
        int l = t + 512 * it;
        float v = colSum[l];
        for (int qi = 0; qi < NL; qi++)
            part[qi] += ((l >> (NL - 1 - qi)) & 1) ? -v : v;
    }
    for (int qi = 0; qi < NL; qi++) {
        red[t] = part[qi];
        __syncthreads();
        for (int off = 256; off > 0; off >>= 1) {
            if (t < off) red[t] += red[t + off];
            __syncthreads();
        }
        if (t == 0) out[NH + qi] = red[0];
        __syncthreads();
    }
}

extern "C" void kernel_launch(void* const* d_in, const int* in_sizes, int n_in,
                              void* d_out, int out_size, void* d_ws, size_t ws_size,
                              hipStream_t stream) {
    const float* feat   = (const float*)d_in[0];   // 22
    const float* adj    = (const float*)d_in[1];   // 22*22
    const float* params = (const float*)d_in[2];   // 3*22
    float* out = (float*)d_out;                    // 22 f32

    char* ws = (char*)d_ws;
    float*    state  = (float*)ws;                              // 4M floats = 16 MB
    float*    w      = (float*)(ws + ((size_t)1 << 24));        // 512
    float*    u      = w + HD;                                  // 8192
    unsigned* sigh   = (unsigned*)(u + LD);                     // 512
    unsigned* lowvs  = sigh + HD;                               // 8192
    float2*   cs1    = (float2*)(lowvs + LD);                   // 22 (8B-aligned offset)
    float2*   cs2    = cs1 + NQ;                                // 22
    float*    rowSum = (float*)(cs2 + NQ);                      // 512
    float*    colSum = rowSum + HD;                             // 8192

    k0_tables<<<dim3(32), dim3(256), 0, stream>>>(feat, adj, params, w, u, sigh, lowvs,
                                                  cs1, cs2, rowSum);
    // layer 1 (params[1]) low + [init = features+params[0]+sign analytically]
    k_low<<<dim3(512), dim3(256), 0, stream>>>(state, w, u, sigh, lowvs, cs1, 1);
    // layer 1 high + sign
    k_high<<<dim3(512), dim3(256), 0, stream>>>(state, sigh, lowvs, cs1);
    // layer 2 (params[2]) low
    k_low<<<dim3(512), dim3(256), 0, stream>>>(state, w, u, sigh, lowvs, cs2, 0);
    // layer 2 high + probs + marginals (final sign irrelevant for probs)
    k_high_final<<<dim3(512), dim3(256), 0, stream>>>(state, cs2, rowSum, colSum);
    // expectations
    k_expect<<<dim3(1), dim3(512), 0, stream>>>(rowSum, colSum, out);
}